// Round 7
// baseline (196.109 us; speedup 1.0000x reference)
//
#include <hip/hip_runtime.h>
#include <hip/hip_bf16.h>

#define BD 4096
#define ID 1024
#define FD 2048
#define NT 96   // K-steps: 64 (hidden@M, K=2048) + 32 (inputs@W_in, K=1024)

typedef __bf16 v8bf __attribute__((ext_vector_type(8)));
typedef float  v4f  __attribute__((ext_vector_type(4)));

struct alignas(8) bf4 { __hip_bfloat16 x, y, z, w; };

__device__ inline __hip_bfloat16 bf(float f) { return __float2bfloat16(f); }
__device__ inline float sig(float x) { return 1.f / (1.f + expf(-x)); }

__device__ inline void gload16(const __hip_bfloat16* g, __hip_bfloat16* l) {
  __builtin_amdgcn_global_load_lds(
      (const __attribute__((address_space(1))) void*)g,
      (__attribute__((address_space(3))) void*)l, 16, 0, 0);
}

// ---------- quantum state prep (+ zero accumulators) ----------
__global__ void k_prep_q(const float* ar, const float* ai, const float* ph,
                         const int* tstep, float* qs, float* pamp,
                         float* scal, float* tau_raw, float* dec_raw) {
  int j = blockIdx.x * 256 + threadIdx.x;
  if (j < 4) scal[j] = 0.f;
  if (j < FD) { tau_raw[j] = 0.f; dec_raw[j] = 0.f; }
  if (j >= FD) return;
  float t = (float)tstep[0];
  float4 a = ((const float4*)ar)[j];
  float4 b = ((const float4*)ai)[j];
  float4 p = ((const float4*)ph)[j];
  float sr = 0.f, si = 0.f, pm = 0.f;
  {
    float c, s, rc, ic;
    c = cosf(p.x + 0.1f * t); s = sinf(p.x + 0.1f * t);
    rc = a.x * c; ic = b.x * s; sr += rc; si += ic; pm += rc * rc + ic * ic;
    c = cosf(p.y + 0.1f * t); s = sinf(p.y + 0.1f * t);
    rc = a.y * c; ic = b.y * s; sr += rc; si += ic; pm += rc * rc + ic * ic;
    c = cosf(p.z + 0.1f * t); s = sinf(p.z + 0.1f * t);
    rc = a.z * c; ic = b.z * s; sr += rc; si += ic; pm += rc * rc + ic * ic;
    c = cosf(p.w + 0.1f * t); s = sinf(p.w + 0.1f * t);
    rc = a.w * c; ic = b.w * s; sr += rc; si += ic; pm += rc * rc + ic * ic;
  }
  qs[j] = sr * expf(-si * si);
  pamp[j] = 0.25f * pm;
}

// ---------- f32 -> bf16 cast: inputs then hidden in one launch ----------
__global__ void k_cast(const float* s1, __hip_bfloat16* d1, int n1,
                       const float* s2, __hip_bfloat16* d2) {
  int i = blockIdx.x * blockDim.x + threadIdx.x;
  const float* src = s1; __hip_bfloat16* dst = d1;
  if (i >= n1) { i -= n1; src = s2; dst = d2; }
  float4 v = ((const float4*)src)[i];
  bf4 o{bf(v.x), bf(v.y), bf(v.z), bf(v.w)};
  ((bf4*)dst)[i] = o;
}

// ---------- transpose + cast (+ optional M = P + E*corr[col]) ----------
// src [R][C] f32 -> dst [C][R] bf16
__global__ void k_tcast(const float* src, const float* src2, const float* corr,
                        __hip_bfloat16* dst, int R, int C, int useM) {
  __shared__ float t[32][33];
  int tx = threadIdx.x, ty = threadIdx.y;   // block (32,8)
  int x = blockIdx.x * 32 + tx;             // src col
  int yb = blockIdx.y * 32;                 // src row base
  float cr = useM ? corr[x] : 0.f;
#pragma unroll
  for (int j = 0; j < 4; j++) {
    int y = yb + ty + j * 8;
    float v = src[(size_t)y * C + x];
    if (useM) v += src2[(size_t)y * C + x] * cr;
    t[ty + j * 8][tx] = v;
  }
  __syncthreads();
#pragma unroll
  for (int j = 0; j < 4; j++) {
    int orow = blockIdx.x * 32 + ty + j * 8;  // = src col
    int ocol = yb + tx;                       // = src row
    dst[(size_t)orow * R + ocol] = bf(t[tx][ty + j * 8]);
  }
}

// ---------- split-K matvec: raw[j] += sum_i qs[i] * W[i][j] ----------
__global__ void k_matvec(const float* qs, const float* Wt, const float* Wd,
                         float* tau_raw, float* dec_raw) {
  int j = blockIdx.x * 256 + threadIdx.x;     // grid.x = 8
  int i0 = blockIdx.y * 128;                  // grid.y = 16
  const float* W = blockIdx.z ? Wd : Wt;      // grid.z = 2
  float* out = blockIdx.z ? dec_raw : tau_raw;
  __shared__ float q[128];
  if (threadIdx.x < 128) q[threadIdx.x] = qs[i0 + threadIdx.x];
  __syncthreads();
  float acc = 0.f;
#pragma unroll 8
  for (int i = 0; i < 128; i++) acc = fmaf(q[i], W[(size_t)(i0 + i) * FD + j], acc);
  atomicAdd(&out[j], acc);
}

// ---------- post: tau_q, s, deco, qact, scalar partials ----------
__global__ void k_post(const float* tau_raw, const float* dec_raw, const float* qs,
                       const float* b_tau, const float* b_dec, const int* tstep,
                       float* s_arr, float* qact, float* scal) {
  int j = blockIdx.x * 256 + threadIdx.x;
  float t = (float)tstep[0];
  float coh = expf(-0.01f * t);
  float tq = (5.f + 45.f * sig(tau_raw[j] + b_tau[j])) / 3.2f;
  s_arr[j] = 0.03125f / tq;                  // dt_q / tau_q, dt_q = 0.1/3.2
  float dec = sig(dec_raw[j] + b_dec[j]);
  qact[j] = qs[j] * dec * coh;
  float tsum = tq, dsum = dec;
  for (int off = 32; off; off >>= 1) {
    tsum += __shfl_down(tsum, off);
    dsum += __shfl_down(dsum, off);
  }
  __shared__ float rt[4], rd[4];
  int w = threadIdx.x >> 6;
  if ((threadIdx.x & 63) == 0) { rt[w] = tsum; rd[w] = dsum; }
  __syncthreads();
  if (threadIdx.x == 0) {
    atomicAdd(&scal[1], rd[0] + rd[1] + rd[2] + rd[3]);
    atomicAdd(&scal[2], rt[0] + rt[1] + rt[2] + rt[3]);
  }
}

// ---------- GEMM + fused h-update epilogue (f32 out) ----------
// Block tile 256x128, 4 waves (wave tile 128x64), grid 16x16 = 1 block/CU.
// Deep-prefetch ring: 4 LDS buffers, depth-3, counted vmcnt (never 0 in loop),
// raw s_barrier. One barrier per K-step:
//   vmcnt(12) [retire stage t] -> barrier -> stage(t+3) -> compute(t)
// Buffer (t+3)&3 == (t-1)&3 is only overwritten after the barrier proving all
// waves finished compute(t-1). XOR-swizzled LDS (write-side on global source,
// read-side on ds_read addr) -- proven conflict-free in round 6.
__global__ __launch_bounds__(256, 1) void k_gemm(
    const __hip_bfloat16* __restrict__ Ah,   // hidden bf16 [BD][FD]
    const __hip_bfloat16* __restrict__ MT,   // [FD][FD]  (B stored [N][K])
    const __hip_bfloat16* __restrict__ Ax,   // inputs bf16 [BD][ID]
    const __hip_bfloat16* __restrict__ WT,   // [FD][ID]
    const float* __restrict__ b_in, const float* __restrict__ s_arr,
    const float* __restrict__ qact,
    float* ent_sum, float* __restrict__ out) {
  __shared__ alignas(16) __hip_bfloat16 As[4][256][32];   // 64 KB
  __shared__ alignas(16) __hip_bfloat16 Bs[4][128][32];   // 32 KB
  __shared__ float red[4];

  const int tid = threadIdx.x;
  const int l = tid & 63, w = tid >> 6;
  const int wr = w >> 1, wc = w & 1;     // wave tile: 128 rows x 64 cols
  const int row0 = blockIdx.x * 256, col0 = blockIdx.y * 128;

  v4f acc[8][4];
#pragma unroll
  for (int i = 0; i < 8; i++)
#pragma unroll
    for (int j = 0; j < 4; j++) acc[i][j] = (v4f)0.f;

  // write-side swizzle: lane l stages global (row l>>2, colblk (l&3)^((l>>3)&3))
  const int srow = l >> 2;
  const int scol = ((l & 3) ^ ((l >> 3) & 3)) * 8;
  // read-side swizzle: colblk' = (l>>4) ^ ((l>>1)&3)
  const int rcol = ((l >> 4) ^ ((l >> 1) & 3)) * 8;

  // stage K-step t into ring buffer t&3: wave w owns A rows [w*64,w*64+64),
  // B rows [w*32,w*32+32). 6 gload_lds per wave per stage.
  auto stage = [&](int t) {
    int buf = t & 3;
    const __hip_bfloat16* A = (t < 64) ? Ah : Ax;
    const __hip_bfloat16* B = (t < 64) ? MT : WT;
    int ld = (t < 64) ? FD : ID;
    int k = (t & 63) * 32;
#pragma unroll
    for (int i = 0; i < 4; i++)
      gload16(A + (size_t)(row0 + w * 64 + i * 16 + srow) * ld + k + scol,
              &As[buf][w * 64 + i * 16][0]);
#pragma unroll
    for (int i = 0; i < 2; i++)
      gload16(B + (size_t)(col0 + w * 32 + i * 16 + srow) * ld + k + scol,
              &Bs[buf][w * 32 + i * 16][0]);
  };
  auto compute = [&](int t) {
    int buf = t & 3;
    v8bf a[8], b[4];
#pragma unroll
    for (int mi = 0; mi < 8; mi++)
      a[mi] = *(const v8bf*)&As[buf][wr * 128 + mi * 16 + (l & 15)][rcol];
#pragma unroll
    for (int ni = 0; ni < 4; ni++)
      b[ni] = *(const v8bf*)&Bs[buf][wc * 64 + ni * 16 + (l & 15)][rcol];
#pragma unroll
    for (int mi = 0; mi < 8; mi++)
#pragma unroll
      for (int ni = 0; ni < 4; ni++)
        acc[mi][ni] = __builtin_amdgcn_mfma_f32_16x16x32_bf16(a[mi], b[ni], acc[mi][ni], 0, 0, 0);
  };

  // prologue: stages 0..2 in strict issue order (vmcnt counting relies on it)
  stage(0);
  __builtin_amdgcn_sched_barrier(0);
  stage(1);
  __builtin_amdgcn_sched_barrier(0);
  stage(2);

  float asum = 0.f;

  for (int t = 0; t < NT - 2; t++) {
    asm volatile("s_waitcnt vmcnt(12)" ::: "memory");   // retire stage(t); t+1,t+2 stay in flight
    __builtin_amdgcn_s_barrier();                       // all waves' stage(t) visible; buf t-1 free
    __builtin_amdgcn_sched_barrier(0);
    if (t + 3 < NT) stage(t + 3);
    compute(t);
    if (t == 63) {                                      // ent phase done: capture |ent|
#pragma unroll
      for (int mi = 0; mi < 8; mi++)
#pragma unroll
        for (int ni = 0; ni < 4; ni++)
#pragma unroll
          for (int e = 0; e < 4; e++) asum += fabsf(acc[mi][ni][e]);
    }
  }
  asm volatile("s_waitcnt vmcnt(6)" ::: "memory");
  __builtin_amdgcn_s_barrier();
  __builtin_amdgcn_sched_barrier(0);
  compute(NT - 2);
  asm volatile("s_waitcnt vmcnt(0)" ::: "memory");
  __builtin_amdgcn_s_barrier();
  __builtin_amdgcn_sched_barrier(0);
  compute(NT - 1);

  // block-reduce |ent|
  for (int off = 32; off; off >>= 1) asum += __shfl_down(asum, off);
  if (l == 0) red[w] = asum;
  __syncthreads();
  if (tid == 0) atomicAdd(ent_sum, red[0] + red[1] + red[2] + red[3]);

  // fused epilogue: out = h + s*(tanh(g+b)+qact - h)   (bf16 h, f32 stores)
#pragma unroll
  for (int ni = 0; ni < 4; ni++) {
    int gc = col0 + wc * 64 + ni * 16 + (l & 15);
    float bi = b_in[gc], qa = qact[gc], sj = s_arr[gc];
#pragma unroll
    for (int mi = 0; mi < 8; mi++) {
      int gr0 = row0 + wr * 128 + mi * 16 + (l >> 4) * 4;
#pragma unroll
      for (int e = 0; e < 4; e++) {
        int gr = gr0 + e;
        float comb = tanhf(acc[mi][ni][e] + bi) + qa;
        float h = __bfloat162float(Ah[(size_t)gr * FD + gc]);
        out[(size_t)gr * FD + gc] = fmaf(sj, comb - h, h);
      }
    }
  }
}

// ---------- d_amp broadcast + scalar finalize ----------
__global__ void k_damp(const float* __restrict__ pamp, const float* scal,
                       const int* tstep, float* __restrict__ out1, float* out3) {
  int i = blockIdx.x * 256 + threadIdx.x;     // float4 index
  int c = (i * 4) & (FD - 1);
  ((float4*)out1)[i] = *(const float4*)&pamp[c];
  if (i == 0) {
    float t = (float)tstep[0];
    out3[0] = expf(-0.01f * t);
    out3[1] = scal[0] / (float)((size_t)BD * FD);
    out3[2] = scal[1] / (float)FD;
    out3[3] = scal[2] / (float)FD;
  }
}

extern "C" void kernel_launch(void* const* d_in, const int* in_sizes, int n_in,
                              void* d_out, int out_size, void* d_ws, size_t ws_size,
                              hipStream_t stream) {
  const float* inputs  = (const float*)d_in[0];
  const float* hidden  = (const float*)d_in[1];
  const float* W_in    = (const float*)d_in[2];
  const float* b_in    = (const float*)d_in[3];
  const float* amp_r   = (const float*)d_in[4];
  const float* amp_i   = (const float*)d_in[5];
  const float* phase   = (const float*)d_in[6];
  const float* primary = (const float*)d_in[7];
  const float* ent_mat = (const float*)d_in[8];
  const float* corr    = (const float*)d_in[9];
  const float* W_tau   = (const float*)d_in[10];
  const float* b_tau   = (const float*)d_in[11];
  const float* W_dec   = (const float*)d_in[12];
  const float* b_dec   = (const float*)d_in[13];
  const int*   tstep   = (const int*)d_in[14];

  char* ws = (char*)d_ws;
  __hip_bfloat16* inputs_bf = (__hip_bfloat16*)(ws + 0);         //  8 MB
  __hip_bfloat16* hidden_bf = (__hip_bfloat16*)(ws + 8388608);   // 16 MB
  __hip_bfloat16* WT        = (__hip_bfloat16*)(ws + 25165824);  //  4 MB
  __hip_bfloat16* MT        = (__hip_bfloat16*)(ws + 29360128);  //  8 MB
  char* sb = ws + 37748736;
  float* scal    = (float*)(sb);          // [0]=ent_sum [1]=dec_sum [2]=tau_sum
  float* qs      = (float*)(sb + 16);
  float* pamp    = (float*)(sb + 16 + 8192);
  float* tau_raw = (float*)(sb + 16 + 2 * 8192);
  float* dec_raw = (float*)(sb + 16 + 3 * 8192);
  float* s_arr   = (float*)(sb + 16 + 4 * 8192);
  float* qact    = (float*)(sb + 16 + 5 * 8192);

  float* out = (float*)d_out;

  hipLaunchKernelGGL(k_prep_q, dim3(8), dim3(256), 0, stream,
                     amp_r, amp_i, phase, tstep, qs, pamp, scal, tau_raw, dec_raw);
  hipLaunchKernelGGL(k_cast, dim3(12288), dim3(256), 0, stream,
                     inputs, inputs_bf, BD * ID / 4, hidden, hidden_bf);
  hipLaunchKernelGGL(k_tcast, dim3(64, 32), dim3(32, 8), 0, stream,
                     W_in, (const float*)nullptr, (const float*)nullptr, WT, ID, FD, 0);
  hipLaunchKernelGGL(k_tcast, dim3(64, 64), dim3(32, 8), 0, stream,
                     primary, ent_mat, corr, MT, FD, FD, 1);
  hipLaunchKernelGGL(k_matvec, dim3(8, 16, 2), dim3(256), 0, stream, qs, W_tau, W_dec, tau_raw, dec_raw);
  hipLaunchKernelGGL(k_post, dim3(8), dim3(256), 0, stream, tau_raw, dec_raw, qs, b_tau, b_dec, tstep, s_arr, qact, scal);
  hipLaunchKernelGGL(k_gemm, dim3(16, 16), dim3(256), 0, stream,
                     hidden_bf, MT, inputs_bf, WT, b_in, s_arr, qact,
                     &scal[0], out);
  hipLaunchKernelGGL(k_damp, dim3(8192), dim3(256), 0, stream,
                     pamp, scal, tstep, out + (size_t)BD * FD, out + (size_t)2 * BD * FD);
}

// Round 8
// 167.516 us; speedup vs baseline: 1.1707x; 1.1707x over previous
//
#include <hip/hip_runtime.h>
#include <hip/hip_bf16.h>
#include <stdint.h>

#define BD 4096
#define ID 1024
#define FD 2048

typedef float v4f __attribute__((ext_vector_type(4)));
typedef int   v4i __attribute__((ext_vector_type(4)));
typedef int   v8i __attribute__((ext_vector_type(8)));

__device__ inline float sig(float x) { return 1.f / (1.f + expf(-x)); }

__device__ inline void gload16(const uint8_t* g, uint8_t* l) {
  __builtin_amdgcn_global_load_lds(
      (const __attribute__((address_space(1))) void*)g,
      (__attribute__((address_space(3))) void*)l, 16, 0, 0);
}

// ---------- quantum state prep (+ zero accumulators) ----------
__global__ void k_prep_q(const float* ar, const float* ai, const float* ph,
                         const int* tstep, float* qs, float* pamp,
                         float* scal, float* tau_raw, float* dec_raw) {
  int j = blockIdx.x * 256 + threadIdx.x;
  if (j < 4) scal[j] = 0.f;
  if (j < FD) { tau_raw[j] = 0.f; dec_raw[j] = 0.f; }
  if (j >= FD) return;
  float t = (float)tstep[0];
  float4 a = ((const float4*)ar)[j];
  float4 b = ((const float4*)ai)[j];
  float4 p = ((const float4*)ph)[j];
  float sr = 0.f, si = 0.f, pm = 0.f;
  {
    float c, s, rc, ic;
    c = cosf(p.x + 0.1f * t); s = sinf(p.x + 0.1f * t);
    rc = a.x * c; ic = b.x * s; sr += rc; si += ic; pm += rc * rc + ic * ic;
    c = cosf(p.y + 0.1f * t); s = sinf(p.y + 0.1f * t);
    rc = a.y * c; ic = b.y * s; sr += rc; si += ic; pm += rc * rc + ic * ic;
    c = cosf(p.z + 0.1f * t); s = sinf(p.z + 0.1f * t);
    rc = a.z * c; ic = b.z * s; sr += rc; si += ic; pm += rc * rc + ic * ic;
    c = cosf(p.w + 0.1f * t); s = sinf(p.w + 0.1f * t);
    rc = a.w * c; ic = b.w * s; sr += rc; si += ic; pm += rc * rc + ic * ic;
  }
  qs[j] = sr * expf(-si * si);
  pamp[j] = 0.25f * pm;
}

// ---------- f32 -> fp8 e4m3 cast: inputs then hidden, 8 elems/thread ----------
__global__ void k_cast8(const float* s1, uint8_t* d1, int n1,
                        const float* s2, uint8_t* d2) {
  int i = blockIdx.x * blockDim.x + threadIdx.x;   // 8-elem unit index
  const float* src = s1; uint8_t* dst = d1;
  if (i >= n1) { i -= n1; src = s2; dst = d2; }
  float4 v0 = ((const float4*)src)[i * 2];
  float4 v1 = ((const float4*)src)[i * 2 + 1];
  int p0 = __builtin_amdgcn_cvt_pk_fp8_f32(v0.x, v0.y, 0, 0);
  p0 = __builtin_amdgcn_cvt_pk_fp8_f32(v0.z, v0.w, p0, 1);
  int p1 = __builtin_amdgcn_cvt_pk_fp8_f32(v1.x, v1.y, 0, 0);
  p1 = __builtin_amdgcn_cvt_pk_fp8_f32(v1.z, v1.w, p1, 1);
  ((int2*)dst)[i] = make_int2(p0, p1);
}

// ---------- transpose + cast to fp8 (+ optional M = P + E*corr[col]) ----------
// src [R][C] f32 -> dst [C][R] fp8
__global__ void k_tcast8(const float* src, const float* src2, const float* corr,
                         uint8_t* dst, int R, int C, int useM) {
  __shared__ float t[32][33];
  int tx = threadIdx.x, ty = threadIdx.y;   // block (32,8)
  int x = blockIdx.x * 32 + tx;             // src col
  int yb = blockIdx.y * 32;                 // src row base
  float cr = useM ? corr[x] : 0.f;
#pragma unroll
  for (int j = 0; j < 4; j++) {
    int y = yb + ty + j * 8;
    float v = src[(size_t)y * C + x];
    if (useM) v += src2[(size_t)y * C + x] * cr;
    t[ty + j * 8][tx] = v;
  }
  __syncthreads();
  int tid = ty * 32 + tx;
  int dr = tid >> 3;            // dst row local (= src col local)
  int dc0 = (tid & 7) * 4;      // dst col local (= src row local)
  float a0 = t[dc0 + 0][dr], a1 = t[dc0 + 1][dr];
  float a2 = t[dc0 + 2][dr], a3 = t[dc0 + 3][dr];
  int p = __builtin_amdgcn_cvt_pk_fp8_f32(a0, a1, 0, 0);
  p = __builtin_amdgcn_cvt_pk_fp8_f32(a2, a3, p, 1);
  *(int*)&dst[(size_t)(blockIdx.x * 32 + dr) * R + yb + dc0] = p;
}

// ---------- split-K matvec: raw[j] += sum_i qs[i] * W[i][j]  (f32) ----------
__global__ void k_matvec(const float* qs, const float* Wt, const float* Wd,
                         float* tau_raw, float* dec_raw) {
  int j = blockIdx.x * 256 + threadIdx.x;     // grid.x = 8
  int i0 = blockIdx.y * 128;                  // grid.y = 16
  const float* W = blockIdx.z ? Wd : Wt;      // grid.z = 2
  float* out = blockIdx.z ? dec_raw : tau_raw;
  __shared__ float q[128];
  if (threadIdx.x < 128) q[threadIdx.x] = qs[i0 + threadIdx.x];
  __syncthreads();
  float acc = 0.f;
#pragma unroll 8
  for (int i = 0; i < 128; i++) acc = fmaf(q[i], W[(size_t)(i0 + i) * FD + j], acc);
  atomicAdd(&out[j], acc);
}

// ---------- post: tau_q, s, deco, qact, scalar partials ----------
__global__ void k_post(const float* tau_raw, const float* dec_raw, const float* qs,
                       const float* b_tau, const float* b_dec, const int* tstep,
                       float* s_arr, float* qact, float* scal) {
  int j = blockIdx.x * 256 + threadIdx.x;
  float t = (float)tstep[0];
  float coh = expf(-0.01f * t);
  float tq = (5.f + 45.f * sig(tau_raw[j] + b_tau[j])) / 3.2f;
  s_arr[j] = 0.03125f / tq;                  // dt_q / tau_q, dt_q = 0.1/3.2
  float dec = sig(dec_raw[j] + b_dec[j]);
  qact[j] = qs[j] * dec * coh;
  float tsum = tq, dsum = dec;
  for (int off = 32; off; off >>= 1) {
    tsum += __shfl_down(tsum, off);
    dsum += __shfl_down(dsum, off);
  }
  __shared__ float rt[4], rd[4];
  int w = threadIdx.x >> 6;
  if ((threadIdx.x & 63) == 0) { rt[w] = tsum; rd[w] = dsum; }
  __syncthreads();
  if (threadIdx.x == 0) {
    atomicAdd(&scal[1], rd[0] + rd[1] + rd[2] + rd[3]);
    atomicAdd(&scal[2], rt[0] + rt[1] + rt[2] + rt[3]);
  }
}

// ---------- MX-fp8 GEMM (scale=1.0) + fused h-update epilogue ----------
// Tile 128x64, BK=128 fp8 -> 24 K-steps total (16 ent + 8 xproj).
// Round-6-proven 2-barrier dbuf skeleton; gload_lds width-16 linear dest;
// XOR swizzle kblk^(row&7) applied on global source (write) + ds_read (read):
// conflict-free under the quarter-wave (16 lane x 16B = 256B) bank model.
__global__ __launch_bounds__(256) void k_gemm(
    const uint8_t* __restrict__ Ah,   // hidden fp8 [BD][FD]
    const uint8_t* __restrict__ MT,   // [FD][FD]  (B stored [N][K])
    const uint8_t* __restrict__ Ax,   // inputs fp8 [BD][ID]
    const uint8_t* __restrict__ WT,   // [FD][ID]
    const float* __restrict__ hidden, // f32 [BD][FD]
    const float* __restrict__ b_in, const float* __restrict__ s_arr,
    const float* __restrict__ qact,
    float* ent_sum, float* __restrict__ out) {
  __shared__ alignas(16) uint8_t As[2][128][128];   // 32 KB
  __shared__ alignas(16) uint8_t Bs[2][64][128];    // 16 KB
  __shared__ float red[4];

  const int tid = threadIdx.x;
  const int l = tid & 63, w = tid >> 6;
  const int wr = w >> 1, wc = w & 1;     // wave tile: 64 rows x 32 cols
  const int row0 = blockIdx.x * 128, col0 = blockIdx.y * 64;

  v4f acc[4][2];
#pragma unroll
  for (int i = 0; i < 4; i++)
#pragma unroll
    for (int j = 0; j < 2; j++) acc[i][j] = (v4f)0.f;

  // write-side: gload16 covers 8 rows x 128B; lane l -> row l>>3, 16B-block l&7.
  // source block pre-permuted: (l&7) ^ (l>>3)  (stays within the 128B row).
  const int srow = l >> 3;
  const int scol = ((l & 7) ^ srow) * 16;

  auto stage = [&](int buf, const uint8_t* A, int lda,
                   const uint8_t* B, int ldb, int k) {
#pragma unroll
    for (int i = 0; i < 4; i++)
      gload16(A + (size_t)(row0 + w * 32 + i * 8 + srow) * lda + k + scol,
              &As[buf][w * 32 + i * 8][0]);
#pragma unroll
    for (int i = 0; i < 2; i++)
      gload16(B + (size_t)(col0 + w * 16 + i * 8 + srow) * ldb + k + scol,
              &Bs[buf][w * 16 + i * 8][0]);
  };

  auto compute = [&](int buf) {
    const int s2 = (l >> 4) * 2, sw = l & 7;
    v8i a[4], b[2];
#pragma unroll
    for (int mi = 0; mi < 4; mi++) {
      int r = wr * 64 + mi * 16 + (l & 15);
      v4i lo = *(const v4i*)&As[buf][r][((s2 + 0) ^ sw) * 16];
      v4i hi = *(const v4i*)&As[buf][r][((s2 + 1) ^ sw) * 16];
      v8i af;
      af[0] = lo[0]; af[1] = lo[1]; af[2] = lo[2]; af[3] = lo[3];
      af[4] = hi[0]; af[5] = hi[1]; af[6] = hi[2]; af[7] = hi[3];
      a[mi] = af;
    }
#pragma unroll
    for (int ni = 0; ni < 2; ni++) {
      int r = wc * 32 + ni * 16 + (l & 15);
      v4i lo = *(const v4i*)&Bs[buf][r][((s2 + 0) ^ sw) * 16];
      v4i hi = *(const v4i*)&Bs[buf][r][((s2 + 1) ^ sw) * 16];
      v8i bf8;
      bf8[0] = lo[0]; bf8[1] = lo[1]; bf8[2] = lo[2]; bf8[3] = lo[3];
      bf8[4] = hi[0]; bf8[5] = hi[1]; bf8[6] = hi[2]; bf8[7] = hi[3];
      b[ni] = bf8;
    }
#pragma unroll
    for (int mi = 0; mi < 4; mi++)
#pragma unroll
      for (int ni = 0; ni < 2; ni++)
        acc[mi][ni] = __builtin_amdgcn_mfma_scale_f32_16x16x128_f8f6f4(
            a[mi], b[ni], acc[mi][ni], 0, 0,      // cbsz=fp8, blgp=fp8
            0, 0x7F7F7F7F, 0, 0x7F7F7F7F);        // scales = 1.0 (E8M0 127)
  };

  // phase 0: ent = hidden @ M   (K = 2048 -> 16 steps)
  stage(0, Ah, FD, MT, FD, 0);
  __syncthreads();
  for (int kt = 0; kt < 16; kt++) {
    if (kt + 1 < 16) stage((kt + 1) & 1, Ah, FD, MT, FD, (kt + 1) * 128);
    compute(kt & 1);
    __syncthreads();
  }

  // |ent| partial (acc currently holds ent_rec tile)
  float asum = 0.f;
#pragma unroll
  for (int mi = 0; mi < 4; mi++)
#pragma unroll
    for (int ni = 0; ni < 2; ni++)
#pragma unroll
      for (int e = 0; e < 4; e++) asum += fabsf(acc[mi][ni][e]);

  // phase 1: += inputs @ W_in   (K = 1024 -> 8 steps)
  stage(0, Ax, ID, WT, ID, 0);
  __syncthreads();
  for (int kt = 0; kt < 8; kt++) {
    if (kt + 1 < 8) stage((kt + 1) & 1, Ax, ID, WT, ID, (kt + 1) * 128);
    compute(kt & 1);
    __syncthreads();
  }

  // block-reduce |ent|
  for (int off = 32; off; off >>= 1) asum += __shfl_down(asum, off);
  if (l == 0) red[w] = asum;
  __syncthreads();
  if (tid == 0) atomicAdd(ent_sum, red[0] + red[1] + red[2] + red[3]);

  // fused epilogue: out = h + s*(tanh(g+b)+qact - h)   (f32 h, f32 stores)
#pragma unroll
  for (int ni = 0; ni < 2; ni++) {
    int gc = col0 + wc * 32 + ni * 16 + (l & 15);
    float bi = b_in[gc], qa = qact[gc], sj = s_arr[gc];
#pragma unroll
    for (int mi = 0; mi < 4; mi++) {
      int gr0 = row0 + wr * 64 + mi * 16 + (l >> 4) * 4;
#pragma unroll
      for (int e = 0; e < 4; e++) {
        int gr = gr0 + e;
        float comb = tanhf(acc[mi][ni][e] + bi) + qa;
        float h = hidden[(size_t)gr * FD + gc];
        out[(size_t)gr * FD + gc] = fmaf(sj, comb - h, h);
      }
    }
  }
}

// ---------- d_amp broadcast + scalar finalize ----------
__global__ void k_damp(const float* __restrict__ pamp, const float* scal,
                       const int* tstep, float* __restrict__ out1, float* out3) {
  int i = blockIdx.x * 256 + threadIdx.x;     // float4 index
  int c = (i * 4) & (FD - 1);
  ((float4*)out1)[i] = *(const float4*)&pamp[c];
  if (i == 0) {
    float t = (float)tstep[0];
    out3[0] = expf(-0.01f * t);
    out3[1] = scal[0] / (float)((size_t)BD * FD);
    out3[2] = scal[1] / (float)FD;
    out3[3] = scal[2] / (float)FD;
  }
}

extern "C" void kernel_launch(void* const* d_in, const int* in_sizes, int n_in,
                              void* d_out, int out_size, void* d_ws, size_t ws_size,
                              hipStream_t stream) {
  const float* inputs  = (const float*)d_in[0];
  const float* hidden  = (const float*)d_in[1];
  const float* W_in    = (const float*)d_in[2];
  const float* b_in    = (const float*)d_in[3];
  const float* amp_r   = (const float*)d_in[4];
  const float* amp_i   = (const float*)d_in[5];
  const float* phase   = (const float*)d_in[6];
  const float* primary = (const float*)d_in[7];
  const float* ent_mat = (const float*)d_in[8];
  const float* corr    = (const float*)d_in[9];
  const float* W_tau   = (const float*)d_in[10];
  const float* b_tau   = (const float*)d_in[11];
  const float* W_dec   = (const float*)d_in[12];
  const float* b_dec   = (const float*)d_in[13];
  const int*   tstep   = (const int*)d_in[14];

  char* ws = (char*)d_ws;
  uint8_t* inputs_f8 = (uint8_t*)(ws + 0);         // 4 MB [4096][1024]
  uint8_t* hidden_f8 = (uint8_t*)(ws + 4194304);   // 8 MB [4096][2048]
  uint8_t* WT        = (uint8_t*)(ws + 12582912);  // 2 MB [2048][1024]
  uint8_t* MT        = (uint8_t*)(ws + 14680064);  // 4 MB [2048][2048]
  char* sb = ws + 18874368;
  float* scal    = (float*)(sb);          // [0]=ent_sum [1]=dec_sum [2]=tau_sum
  float* qs      = (float*)(sb + 16);
  float* pamp    = (float*)(sb + 16 + 8192);
  float* tau_raw = (float*)(sb + 16 + 2 * 8192);
  float* dec_raw = (float*)(sb + 16 + 3 * 8192);
  float* s_arr   = (float*)(sb + 16 + 4 * 8192);
  float* qact    = (float*)(sb + 16 + 5 * 8192);

  float* out = (float*)d_out;

  hipLaunchKernelGGL(k_prep_q, dim3(8), dim3(256), 0, stream,
                     amp_r, amp_i, phase, tstep, qs, pamp, scal, tau_raw, dec_raw);
  hipLaunchKernelGGL(k_cast8, dim3(6144), dim3(256), 0, stream,
                     inputs, inputs_f8, BD * ID / 8, hidden, hidden_f8);
  hipLaunchKernelGGL(k_tcast8, dim3(64, 32), dim3(32, 8), 0, stream,
                     W_in, (const float*)nullptr, (const float*)nullptr, WT, ID, FD, 0);
  hipLaunchKernelGGL(k_tcast8, dim3(64, 64), dim3(32, 8), 0, stream,
                     primary, ent_mat, corr, MT, FD, FD, 1);
  hipLaunchKernelGGL(k_matvec, dim3(8, 16, 2), dim3(256), 0, stream, qs, W_tau, W_dec, tau_raw, dec_raw);
  hipLaunchKernelGGL(k_post, dim3(8), dim3(256), 0, stream, tau_raw, dec_raw, qs, b_tau, b_dec, tstep, s_arr, qact, scal);
  hipLaunchKernelGGL(k_gemm, dim3(32, 32), dim3(256), 0, stream,
                     hidden_f8, MT, inputs_f8, WT, hidden, b_in, s_arr, qact,
                     &scal[0], out);
  hipLaunchKernelGGL(k_damp, dim3(8192), dim3(256), 0, stream,
                     pamp, scal, tstep, out + (size_t)BD * FD, out + (size_t)2 * BD * FD);
}

// Round 9
// 143.178 us; speedup vs baseline: 1.3697x; 1.1700x over previous
//
#include <hip/hip_runtime.h>
#include <hip/hip_bf16.h>

#define BD 4096
#define ID 1024
#define FD 2048
#define NT 96   // K-steps: 64 (hidden@M, K=2048) + 32 (inputs@W_in, K=1024)

typedef __bf16 v8bf __attribute__((ext_vector_type(8)));
typedef float  v4f  __attribute__((ext_vector_type(4)));

struct alignas(8) bf4 { __hip_bfloat16 x, y, z, w; };

__device__ inline __hip_bfloat16 bf(float f) { return __float2bfloat16(f); }
__device__ inline float sig(float x) { return 1.f / (1.f + expf(-x)); }

__device__ inline void gload16(const __hip_bfloat16* g, __hip_bfloat16* l) {
  __builtin_amdgcn_global_load_lds(
      (const __attribute__((address_space(1))) void*)g,
      (__attribute__((address_space(3))) void*)l, 16, 0, 0);
}

// ---------- quantum state prep (+ zero accumulators) ----------
__global__ void k_prep_q(const float* ar, const float* ai, const float* ph,
                         const int* tstep, float* qs, float* pamp,
                         float* scal, float* tau_raw, float* dec_raw) {
  int j = blockIdx.x * 256 + threadIdx.x;
  if (j < 4) scal[j] = 0.f;
  if (j < FD) { tau_raw[j] = 0.f; dec_raw[j] = 0.f; }
  if (j >= FD) return;
  float t = (float)tstep[0];
  float4 a = ((const float4*)ar)[j];
  float4 b = ((const float4*)ai)[j];
  float4 p = ((const float4*)ph)[j];
  float sr = 0.f, si = 0.f, pm = 0.f;
  {
    float c, s, rc, ic;
    c = cosf(p.x + 0.1f * t); s = sinf(p.x + 0.1f * t);
    rc = a.x * c; ic = b.x * s; sr += rc; si += ic; pm += rc * rc + ic * ic;
    c = cosf(p.y + 0.1f * t); s = sinf(p.y + 0.1f * t);
    rc = a.y * c; ic = b.y * s; sr += rc; si += ic; pm += rc * rc + ic * ic;
    c = cosf(p.z + 0.1f * t); s = sinf(p.z + 0.1f * t);
    rc = a.z * c; ic = b.z * s; sr += rc; si += ic; pm += rc * rc + ic * ic;
    c = cosf(p.w + 0.1f * t); s = sinf(p.w + 0.1f * t);
    rc = a.w * c; ic = b.w * s; sr += rc; si += ic; pm += rc * rc + ic * ic;
  }
  qs[j] = sr * expf(-si * si);
  pamp[j] = 0.25f * pm;
}

// ---------- f32 -> bf16 cast: inputs then hidden in one launch ----------
__global__ void k_cast(const float* s1, __hip_bfloat16* d1, int n1,
                       const float* s2, __hip_bfloat16* d2) {
  int i = blockIdx.x * blockDim.x + threadIdx.x;
  const float* src = s1; __hip_bfloat16* dst = d1;
  if (i >= n1) { i -= n1; src = s2; dst = d2; }
  float4 v = ((const float4*)src)[i];
  bf4 o{bf(v.x), bf(v.y), bf(v.z), bf(v.w)};
  ((bf4*)dst)[i] = o;
}

// ---------- transpose + cast (+ optional M = P + E*corr[col]) ----------
// src [R][C] f32 -> dst [C][R] bf16
__global__ void k_tcast(const float* src, const float* src2, const float* corr,
                        __hip_bfloat16* dst, int R, int C, int useM) {
  __shared__ float t[32][33];
  int tx = threadIdx.x, ty = threadIdx.y;   // block (32,8)
  int x = blockIdx.x * 32 + tx;             // src col
  int yb = blockIdx.y * 32;                 // src row base
  float cr = useM ? corr[x] : 0.f;
#pragma unroll
  for (int j = 0; j < 4; j++) {
    int y = yb + ty + j * 8;
    float v = src[(size_t)y * C + x];
    if (useM) v += src2[(size_t)y * C + x] * cr;
    t[ty + j * 8][tx] = v;
  }
  __syncthreads();
#pragma unroll
  for (int j = 0; j < 4; j++) {
    int orow = blockIdx.x * 32 + ty + j * 8;  // = src col
    int ocol = yb + tx;                       // = src row
    dst[(size_t)orow * R + ocol] = bf(t[tx][ty + j * 8]);
  }
}

// ---------- split-K matvec: raw[j] += sum_i qs[i] * W[i][j] ----------
__global__ void k_matvec(const float* qs, const float* Wt, const float* Wd,
                         float* tau_raw, float* dec_raw) {
  int j = blockIdx.x * 256 + threadIdx.x;     // grid.x = 8
  int i0 = blockIdx.y * 128;                  // grid.y = 16
  const float* W = blockIdx.z ? Wd : Wt;      // grid.z = 2
  float* out = blockIdx.z ? dec_raw : tau_raw;
  __shared__ float q[128];
  if (threadIdx.x < 128) q[threadIdx.x] = qs[i0 + threadIdx.x];
  __syncthreads();
  float acc = 0.f;
#pragma unroll 8
  for (int i = 0; i < 128; i++) acc = fmaf(q[i], W[(size_t)(i0 + i) * FD + j], acc);
  atomicAdd(&out[j], acc);
}

// ---------- post: tau_q, s, deco, qact, scalar partials ----------
__global__ void k_post(const float* tau_raw, const float* dec_raw, const float* qs,
                       const float* b_tau, const float* b_dec, const int* tstep,
                       float* s_arr, float* qact, float* scal) {
  int j = blockIdx.x * 256 + threadIdx.x;
  float t = (float)tstep[0];
  float coh = expf(-0.01f * t);
  float tq = (5.f + 45.f * sig(tau_raw[j] + b_tau[j])) / 3.2f;
  s_arr[j] = 0.03125f / tq;                  // dt_q / tau_q, dt_q = 0.1/3.2
  float dec = sig(dec_raw[j] + b_dec[j]);
  qact[j] = qs[j] * dec * coh;
  float tsum = tq, dsum = dec;
  for (int off = 32; off; off >>= 1) {
    tsum += __shfl_down(tsum, off);
    dsum += __shfl_down(dsum, off);
  }
  __shared__ float rt[4], rd[4];
  int w = threadIdx.x >> 6;
  if ((threadIdx.x & 63) == 0) { rt[w] = tsum; rd[w] = dsum; }
  __syncthreads();
  if (threadIdx.x == 0) {
    atomicAdd(&scal[1], rd[0] + rd[1] + rd[2] + rd[3]);
    atomicAdd(&scal[2], rt[0] + rt[1] + rt[2] + rt[3]);
  }
}

// ---------- GEMM + fused h-update epilogue (f32 out) ----------
// 128x64 tile, BK=32, 4 blocks/CU (36KB LDS, ring of 3 buffers).
// Counted-vmcnt pipeline (round-7 protocol, proven correct, re-tiled to the
// round-6 high-occupancy geometry): per K-step
//   vmcnt(3) [stage(t) landed; stage(t+1) in flight] -> s_barrier ->
//   stage(t+2) [overwrites buf (t-1)%3, safe: barrier proved compute(t-1)
//   done by all waves] -> compute(t).
// Never vmcnt(0) inside the loop. XOR-swizzled LDS (0 conflicts, round 6).
__global__ __launch_bounds__(256, 4) void k_gemm(
    const __hip_bfloat16* __restrict__ Ah,   // hidden bf16 [BD][FD]
    const __hip_bfloat16* __restrict__ MT,   // [FD][FD]  (B stored [N][K])
    const __hip_bfloat16* __restrict__ Ax,   // inputs bf16 [BD][ID]
    const __hip_bfloat16* __restrict__ WT,   // [FD][ID]
    const float* __restrict__ b_in, const float* __restrict__ s_arr,
    const float* __restrict__ qact,
    float* ent_sum, float* __restrict__ out) {
  __shared__ alignas(16) __hip_bfloat16 As[3][128][32];   // 24 KB
  __shared__ alignas(16) __hip_bfloat16 Bs[3][64][32];    // 12 KB
  __shared__ float red[4];

  const int tid = threadIdx.x;
  const int l = tid & 63, w = tid >> 6;
  const int wr = w >> 1, wc = w & 1;     // wave tile: 64 rows x 32 cols
  const int row0 = blockIdx.x * 128, col0 = blockIdx.y * 64;

  v4f acc[4][2];
#pragma unroll
  for (int i = 0; i < 4; i++)
#pragma unroll
    for (int j = 0; j < 2; j++) acc[i][j] = (v4f)0.f;

  // write-side swizzle: lane l stages global (row l>>2, colblk (l&3)^((l>>3)&3))
  const int srow = l >> 2;
  const int scol = ((l & 3) ^ ((l >> 3) & 3)) * 8;
  // read-side swizzle: colblk' = (l>>4) ^ ((l>>1)&3)
  const int rcol = ((l >> 4) ^ ((l >> 1) & 3)) * 8;

  // stage K-step t into ring buffer t%3: 3 gload_lds per wave.
  auto stage = [&](int t) {
    int buf = t % 3;
    const __hip_bfloat16* A = (t < 64) ? Ah : Ax;
    const __hip_bfloat16* B = (t < 64) ? MT : WT;
    int ld = (t < 64) ? FD : ID;
    int k = (t & 63) * 32;
    gload16(A + (size_t)(row0 + w * 32 + srow) * ld + k + scol,
            &As[buf][w * 32][0]);
    gload16(A + (size_t)(row0 + w * 32 + 16 + srow) * ld + k + scol,
            &As[buf][w * 32 + 16][0]);
    gload16(B + (size_t)(col0 + w * 16 + srow) * ld + k + scol,
            &Bs[buf][w * 16][0]);
  };
  auto compute = [&](int t) {
    int buf = t % 3;
    v8bf a[4], b[2];
#pragma unroll
    for (int mi = 0; mi < 4; mi++)
      a[mi] = *(const v8bf*)&As[buf][wr * 64 + mi * 16 + (l & 15)][rcol];
#pragma unroll
    for (int ni = 0; ni < 2; ni++)
      b[ni] = *(const v8bf*)&Bs[buf][wc * 32 + ni * 16 + (l & 15)][rcol];
#pragma unroll
    for (int mi = 0; mi < 4; mi++)
#pragma unroll
      for (int ni = 0; ni < 2; ni++)
        acc[mi][ni] = __builtin_amdgcn_mfma_f32_16x16x32_bf16(a[mi], b[ni], acc[mi][ni], 0, 0, 0);
  };

  // prologue: stages 0,1 in issue order (vmcnt counting relies on it)
  stage(0);
  __builtin_amdgcn_sched_barrier(0);
  stage(1);

  float asum = 0.f;

  for (int t = 0; t < NT - 1; t++) {
    asm volatile("s_waitcnt vmcnt(3)" ::: "memory");  // stage(t) landed (mine)
    __builtin_amdgcn_s_barrier();                     // => landed for ALL waves
    __builtin_amdgcn_sched_barrier(0);
    if (t + 2 < NT) stage(t + 2);
    compute(t);
    if (t == 63) {                                    // ent phase done: |ent|
#pragma unroll
      for (int mi = 0; mi < 4; mi++)
#pragma unroll
        for (int ni = 0; ni < 2; ni++)
#pragma unroll
          for (int e = 0; e < 4; e++) asum += fabsf(acc[mi][ni][e]);
    }
  }
  asm volatile("s_waitcnt vmcnt(0)" ::: "memory");
  __builtin_amdgcn_s_barrier();
  __builtin_amdgcn_sched_barrier(0);
  compute(NT - 1);

  // block-reduce |ent|
  for (int off = 32; off; off >>= 1) asum += __shfl_down(asum, off);
  if (l == 0) red[w] = asum;
  __syncthreads();
  if (tid == 0) atomicAdd(ent_sum, red[0] + red[1] + red[2] + red[3]);

  // fused epilogue: out = h + s*(tanh(g+b)+qact - h)   (bf16 h, f32 stores)
#pragma unroll
  for (int ni = 0; ni < 2; ni++) {
    int gc = col0 + wc * 32 + ni * 16 + (l & 15);
    float bi = b_in[gc], qa = qact[gc], sj = s_arr[gc];
#pragma unroll
    for (int mi = 0; mi < 4; mi++) {
      int gr0 = row0 + wr * 64 + mi * 16 + (l >> 4) * 4;
#pragma unroll
      for (int e = 0; e < 4; e++) {
        int gr = gr0 + e;
        float comb = tanhf(acc[mi][ni][e] + bi) + qa;
        float h = __bfloat162float(Ah[(size_t)gr * FD + gc]);
        out[(size_t)gr * FD + gc] = fmaf(sj, comb - h, h);
      }
    }
  }
}

// ---------- d_amp broadcast + scalar finalize ----------
__global__ void k_damp(const float* __restrict__ pamp, const float* scal,
                       const int* tstep, float* __restrict__ out1, float* out3) {
  int i = blockIdx.x * 256 + threadIdx.x;     // float4 index
  int c = (i * 4) & (FD - 1);
  ((float4*)out1)[i] = *(const float4*)&pamp[c];
  if (i == 0) {
    float t = (float)tstep[0];
    out3[0] = expf(-0.01f * t);
    out3[1] = scal[0] / (float)((size_t)BD * FD);
    out3[2] = scal[1] / (float)FD;
    out3[3] = scal[2] / (float)FD;
  }
}

extern "C" void kernel_launch(void* const* d_in, const int* in_sizes, int n_in,
                              void* d_out, int out_size, void* d_ws, size_t ws_size,
                              hipStream_t stream) {
  const float* inputs  = (const float*)d_in[0];
  const float* hidden  = (const float*)d_in[1];
  const float* W_in    = (const float*)d_in[2];
  const float* b_in    = (const float*)d_in[3];
  const float* amp_r   = (const float*)d_in[4];
  const float* amp_i   = (const float*)d_in[5];
  const float* phase   = (const float*)d_in[6];
  const float* primary = (const float*)d_in[7];
  const float* ent_mat = (const float*)d_in[8];
  const float* corr    = (const float*)d_in[9];
  const float* W_tau   = (const float*)d_in[10];
  const float* b_tau   = (const float*)d_in[11];
  const float* W_dec   = (const float*)d_in[12];
  const float* b_dec   = (const float*)d_in[13];
  const int*   tstep   = (const int*)d_in[14];

  char* ws = (char*)d_ws;
  __hip_bfloat16* inputs_bf = (__hip_bfloat16*)(ws + 0);         //  8 MB
  __hip_bfloat16* hidden_bf = (__hip_bfloat16*)(ws + 8388608);   // 16 MB
  __hip_bfloat16* WT        = (__hip_bfloat16*)(ws + 25165824);  //  4 MB
  __hip_bfloat16* MT        = (__hip_bfloat16*)(ws + 29360128);  //  8 MB
  char* sb = ws + 37748736;
  float* scal    = (float*)(sb);          // [0]=ent_sum [1]=dec_sum [2]=tau_sum
  float* qs      = (float*)(sb + 16);
  float* pamp    = (float*)(sb + 16 + 8192);
  float* tau_raw = (float*)(sb + 16 + 2 * 8192);
  float* dec_raw = (float*)(sb + 16 + 3 * 8192);
  float* s_arr   = (float*)(sb + 16 + 4 * 8192);
  float* qact    = (float*)(sb + 16 + 5 * 8192);

  float* out = (float*)d_out;

  hipLaunchKernelGGL(k_prep_q, dim3(8), dim3(256), 0, stream,
                     amp_r, amp_i, phase, tstep, qs, pamp, scal, tau_raw, dec_raw);
  hipLaunchKernelGGL(k_cast, dim3(12288), dim3(256), 0, stream,
                     inputs, inputs_bf, BD * ID / 4, hidden, hidden_bf);
  hipLaunchKernelGGL(k_tcast, dim3(64, 32), dim3(32, 8), 0, stream,
                     W_in, (const float*)nullptr, (const float*)nullptr, WT, ID, FD, 0);
  hipLaunchKernelGGL(k_tcast, dim3(64, 64), dim3(32, 8), 0, stream,
                     primary, ent_mat, corr, MT, FD, FD, 1);
  hipLaunchKernelGGL(k_matvec, dim3(8, 16, 2), dim3(256), 0, stream, qs, W_tau, W_dec, tau_raw, dec_raw);
  hipLaunchKernelGGL(k_post, dim3(8), dim3(256), 0, stream, tau_raw, dec_raw, qs, b_tau, b_dec, tstep, s_arr, qact, scal);
  hipLaunchKernelGGL(k_gemm, dim3(32, 32), dim3(256), 0, stream,
                     hidden_bf, MT, inputs_bf, WT, b_in, s_arr, qact,
                     &scal[0], out);
  hipLaunchKernelGGL(k_damp, dim3(8192), dim3(256), 0, stream,
                     pamp, scal, tstep, out + (size_t)BD * FD, out + (size_t)2 * BD * FD);
}